// Round 1
// baseline (814.267 us; speedup 1.0000x reference)
//
#include <hip/hip_runtime.h>
#include <cstdint>
#include <cstddef>

// Problem constants
#define B_ 8
#define S_ 4096
#define H_ 1024
#define NH_ 16
#define DH_ 64
#define MTOK 32768  // B_*S_

typedef unsigned short u16;
typedef __bf16 bf16x8 __attribute__((ext_vector_type(8)));
typedef u16 u16x8 __attribute__((ext_vector_type(8)));
typedef u16 u16x4 __attribute__((ext_vector_type(4)));
typedef float f32x4 __attribute__((ext_vector_type(4)));

#define DEVFN static __device__ __forceinline__

DEVFN float bf2f(u16 u) {
  union { uint32_t u; float f; } c; c.u = ((uint32_t)u) << 16; return c.f;
}
DEVFN u16 f2bf(float f) {
  union { float f; uint32_t u; } c; c.f = f;
  uint32_t r = c.u + 0x7fffu + ((c.u >> 16) & 1u);  // RNE
  return (u16)(r >> 16);
}
DEVFN void gload16(const void* g, void* lds) {
  __builtin_amdgcn_global_load_lds(
      (const __attribute__((address_space(1))) void*)g,
      (__attribute__((address_space(3))) void*)lds, 16, 0, 0);
}

// ---------------------------------------------------------------------------
// Convert fp32 X -> bf16 Xb
__global__ __launch_bounds__(256) void k_cvt_x(const float* __restrict__ x,
                                               u16* __restrict__ xb) {
  const size_t i = ((size_t)blockIdx.x * 256 + threadIdx.x) * 8;
  f32x4 a = *(const f32x4*)(x + i);
  f32x4 b = *(const f32x4*)(x + i + 4);
  u16x8 o;
#pragma unroll
  for (int j = 0; j < 4; ++j) { o[j] = f2bf(a[j]); o[4 + j] = f2bf(b[j]); }
  *(u16x8*)(xb + i) = o;
}

// ---------------------------------------------------------------------------
// Wt[g*1024+n][k] = W_g[k][n]  (bf16, B^T layout for the GEMM)
__global__ __launch_bounds__(256) void k_wt(const float* __restrict__ Wq,
                                            const float* __restrict__ Wk,
                                            const float* __restrict__ Wv,
                                            u16* __restrict__ Wt) {
  const int n = blockIdx.x * 256 + threadIdx.x;  // 0..1023
  const int kc = blockIdx.y;                     // k-chunk of 8
  const int g = blockIdx.z;                      // 0..2
  const float* W = (g == 0) ? Wq : (g == 1) ? Wk : Wv;
  u16x8 o;
#pragma unroll
  for (int j = 0; j < 8; ++j) o[j] = f2bf(W[(size_t)(kc * 8 + j) * 1024 + n]);
  *(u16x8*)(Wt + ((size_t)(g * 1024 + n)) * 1024 + kc * 8) = o;
}

// ---------------------------------------------------------------------------
// 128x128 bf16 MFMA GEMM, A[M,1024] row-major, Bt[N,1024] (i.e. B^T) row-major.
// EPI=0: QKV epilogue (bias + elu for Q,K; split by col segment of N=3072)
// EPI=1: plain bf16 store (ctx GEMM, Bt indexed per-batch: Bt + b*1M)
template <int EPI>
__global__ __launch_bounds__(256, 2) void k_gemm(
    const u16* __restrict__ A, const u16* __restrict__ Bt,
    u16* __restrict__ o0, u16* __restrict__ o1, u16* __restrict__ o2,
    const float* __restrict__ b0, const float* __restrict__ b1,
    const float* __restrict__ b2) {
  __shared__ u16 As[128 * 32];
  __shared__ u16 Bs[128 * 32];
  const int tid = threadIdx.x;
  const int w = tid >> 6, l = tid & 63;
  const int wm = w >> 1, wn = w & 1;
  const long row0 = (long)blockIdx.x * 128;
  const long col0 = (long)blockIdx.y * 128;
  const u16* Bt2 = Bt;
  if (EPI == 1) Bt2 += ((size_t)(row0 >> 12)) << 20;  // per-batch M2t

  f32x4 acc[4][4];
#pragma unroll
  for (int i = 0; i < 4; ++i)
#pragma unroll
    for (int j = 0; j < 4; ++j) acc[i][j] = (f32x4){0.f, 0.f, 0.f, 0.f};

  // staging: 512 chunks of 16B per tile; chunk c -> row c>>2, k-col (c&3)*8
  const int c0 = tid, c1 = 256 + tid;
  const u16* gA0 = A + (row0 + (c0 >> 2)) * 1024 + (c0 & 3) * 8;
  const u16* gA1 = A + (row0 + (c1 >> 2)) * 1024 + (c1 & 3) * 8;
  const u16* gB0 = Bt2 + (col0 + (c0 >> 2)) * 1024 + (c0 & 3) * 8;
  const u16* gB1 = Bt2 + (col0 + (c1 >> 2)) * 1024 + (c1 & 3) * 8;
  u16* lA0 = As + (w * 64) * 8;          // wave-uniform LDS bases
  u16* lA1 = As + (256 + w * 64) * 8;
  u16* lB0 = Bs + (w * 64) * 8;
  u16* lB1 = Bs + (256 + w * 64) * 8;

  const int aoff = (wm * 64 + (l & 15)) * 32 + (l >> 4) * 8;
  const int boff = (wn * 64 + (l & 15)) * 32 + (l >> 4) * 8;

  for (int kt = 0; kt < 1024; kt += 32) {
    gload16(gA0 + kt, lA0);
    gload16(gA1 + kt, lA1);
    gload16(gB0 + kt, lB0);
    gload16(gB1 + kt, lB1);
    __syncthreads();  // drains vmcnt -> tiles visible
    bf16x8 af[4], bfr[4];
#pragma unroll
    for (int mi = 0; mi < 4; ++mi)
      af[mi] = *(const bf16x8*)(As + aoff + mi * 512);
#pragma unroll
    for (int ni = 0; ni < 4; ++ni)
      bfr[ni] = *(const bf16x8*)(Bs + boff + ni * 512);
#pragma unroll
    for (int mi = 0; mi < 4; ++mi)
#pragma unroll
      for (int ni = 0; ni < 4; ++ni)
        acc[mi][ni] = __builtin_amdgcn_mfma_f32_16x16x32_bf16(
            af[mi], bfr[ni], acc[mi][ni], 0, 0, 0);
    __syncthreads();  // all reads done before next stage overwrites
  }

  // Epilogue: D row = (l>>4)*4+reg, col = l&15 within each 16x16 frag
  const int rb = (int)row0 + wm * 64 + ((l >> 4) << 2);
  const int cb = (int)col0 + wn * 64 + (l & 15);
  if (EPI == 0) {
    const int seg = (int)(col0 >> 10);  // 0:Q 1:K 2:V (uniform per block)
    const int cl = cb & 1023;
    u16* outp = (seg == 0) ? o0 : (seg == 1) ? o1 : o2;
    const float* bias = (seg == 0) ? b0 : (seg == 1) ? b1 : b2;
#pragma unroll
    for (int mi = 0; mi < 4; ++mi)
#pragma unroll
      for (int ni = 0; ni < 4; ++ni) {
        const float bv_ = bias[cl + ni * 16];
#pragma unroll
        for (int r = 0; r < 4; ++r) {
          float v = acc[mi][ni][r] + bv_;
          if (seg < 2) v = v > 0.f ? v : expm1f(v);  // elu
          outp[(size_t)(rb + mi * 16 + r) * 1024 + cl + ni * 16] = f2bf(v);
        }
      }
  } else {
#pragma unroll
    for (int mi = 0; mi < 4; ++mi)
#pragma unroll
      for (int ni = 0; ni < 4; ++ni)
#pragma unroll
        for (int r = 0; r < 4; ++r)
          o0[(size_t)(rb + mi * 16 + r) * 1024 + cb + ni * 16] =
              f2bf(acc[mi][ni][r]);
  }
}

// ---------------------------------------------------------------------------
// Per-(token,head) L2 norms: qn = eq/||eq|| in-place; rk = 1/||ek|| stored.
__global__ __launch_bounds__(256) void k_qnrk(u16* __restrict__ eq,
                                              const u16* __restrict__ ek,
                                              float* __restrict__ rk) {
  const int tid = threadIdx.x, w = tid >> 6, l = tid & 63;
  const long t = (long)blockIdx.x * 4 + w;
  const size_t base = (size_t)t * 1024 + (l >> 2) * 64 + (l & 3) * 16;
  u16x8 a = *(const u16x8*)(eq + base);
  u16x8 b = *(const u16x8*)(eq + base + 8);
  float f[16];
#pragma unroll
  for (int j = 0; j < 8; ++j) { f[j] = bf2f(a[j]); f[8 + j] = bf2f(b[j]); }
  float ss = 0.f;
#pragma unroll
  for (int j = 0; j < 16; ++j) ss += f[j] * f[j];
  ss += __shfl_xor(ss, 1);
  ss += __shfl_xor(ss, 2);
  const float rq = rsqrtf(ss);
  u16x8 oa, ob;
#pragma unroll
  for (int j = 0; j < 8; ++j) { oa[j] = f2bf(f[j] * rq); ob[j] = f2bf(f[8 + j] * rq); }
  *(u16x8*)(eq + base) = oa;
  *(u16x8*)(eq + base + 8) = ob;

  a = *(const u16x8*)(ek + base);
  b = *(const u16x8*)(ek + base + 8);
  float sk = 0.f;
#pragma unroll
  for (int j = 0; j < 8; ++j) {
    float x0 = bf2f(a[j]), x1 = bf2f(b[j]);
    sk += x0 * x0 + x1 * x1;
  }
  sk += __shfl_xor(sk, 1);
  sk += __shfl_xor(sk, 2);
  if ((l & 3) == 0) rk[t * 16 + (l >> 2)] = rsqrtf(sk);
}

// ---------------------------------------------------------------------------
// kv partials: kvp[sc][b][h][d][e] = sum over s-chunk of kn[s,d]*v[s,e]
__global__ __launch_bounds__(256) void k_kv(const u16* __restrict__ ek,
                                            const u16* __restrict__ vv,
                                            const float* __restrict__ rk,
                                            float* __restrict__ kvp) {
  __shared__ float kns[64][68];  // +4 pad: conflict-free staging & reads
  __shared__ float vs[64][68];
  const int tid = threadIdx.x;
  const int bid = blockIdx.x;  // sc + 4*(h + 16*b)
  const int sc = bid & 3, h = (bid >> 2) & 15, b = bid >> 6;
  const int d = tid >> 2, eg = tid & 3;
  float acc[16] = {};
  const long tbase = (long)b * 4096 + sc * 1024;
  for (int st = 0; st < 1024; st += 64) {
    const long t = tbase + st + (tid >> 2);
    const int q = tid & 3;
    const u16* ep = ek + (size_t)t * 1024 + h * 64 + q * 16;
    const u16* vp = vv + (size_t)t * 1024 + h * 64 + q * 16;
    u16x8 e0 = *(const u16x8*)ep, e1 = *(const u16x8*)(ep + 8);
    u16x8 v0 = *(const u16x8*)vp, v1 = *(const u16x8*)(vp + 8);
    const float rkv = rk[t * 16 + h];
    __syncthreads();  // previous tile fully consumed
#pragma unroll
    for (int j = 0; j < 8; ++j) {
      kns[tid >> 2][q * 16 + j] = bf2f(e0[j]) * rkv;
      kns[tid >> 2][q * 16 + 8 + j] = bf2f(e1[j]) * rkv;
      vs[tid >> 2][q * 16 + j] = bf2f(v0[j]);
      vs[tid >> 2][q * 16 + 8 + j] = bf2f(v1[j]);
    }
    __syncthreads();
    for (int s = 0; s < 64; ++s) {
      const float kn = kns[s][d];
      const f32x4* vr = (const f32x4*)&vs[s][eg * 16];
      f32x4 q0 = vr[0], q1 = vr[1], q2 = vr[2], q3 = vr[3];
#pragma unroll
      for (int j = 0; j < 4; ++j) {
        acc[j] += kn * q0[j];
        acc[4 + j] += kn * q1[j];
        acc[8 + j] += kn * q2[j];
        acc[12 + j] += kn * q3[j];
      }
    }
  }
  float* op = kvp + (((size_t)(sc * 8 + b) * 16 + h) * 64 + d) * 64 + eg * 16;
#pragma unroll
  for (int c = 0; c < 4; ++c) {
    f32x4 o = {acc[c * 4], acc[c * 4 + 1], acc[c * 4 + 2], acc[c * 4 + 3]};
    *(f32x4*)(op + c * 4) = o;
  }
}

// ---------------------------------------------------------------------------
// M2t[b][n][h*64+d] = (1/8) * sum_e kv[b,h][d][e] * Wd[h*64+e][n]   (bf16)
__global__ __launch_bounds__(256) void k_m2(const float* __restrict__ kvp,
                                            const float* __restrict__ Wd,
                                            u16* __restrict__ M2t) {
  const int tid = threadIdx.x;
  const int nb = blockIdx.x, h = blockIdx.y, b = blockIdx.z;
  const int d = tid >> 2, eg = tid & 3;
  const size_t kbase = (((size_t)(b * 16 + h)) * 64 + d) * 64 + eg * 16;
  float kvr[16];
#pragma unroll
  for (int c = 0; c < 4; ++c) {
    f32x4 s = *(const f32x4*)(kvp + kbase + c * 4);
#pragma unroll
    for (int sc = 1; sc < 4; ++sc)
      s += *(const f32x4*)(kvp + (size_t)sc * 524288 + kbase + c * 4);
#pragma unroll
    for (int j = 0; j < 4; ++j) kvr[c * 4 + j] = s[j];
  }
  const float* wcol = Wd + ((size_t)h * 64 + eg * 16) * 1024;
  for (int n = nb * 256; n < nb * 256 + 256; ++n) {
    float p = 0.f;
#pragma unroll
    for (int i = 0; i < 16; ++i) p += kvr[i] * wcol[(size_t)i * 1024 + n];
    p += __shfl_xor(p, 1);
    p += __shfl_xor(p, 2);
    if (eg == 0)
      M2t[((size_t)b * 1024 + n) * 1024 + h * 64 + d] = f2bf(p * 0.125f);
  }
}

// ---------------------------------------------------------------------------
// LayerNorm(hid + bd + x) * gamma + beta  -> fp32 out
__global__ __launch_bounds__(256) void k_ln(const u16* __restrict__ hid,
                                            const float* __restrict__ x,
                                            const float* __restrict__ bd,
                                            const float* __restrict__ g,
                                            const float* __restrict__ be,
                                            float* __restrict__ out) {
  const int tid = threadIdx.x, w = tid >> 6, l = tid & 63;
  const size_t base = (size_t)blockIdx.x * 1024 + tid * 4;
  u16x4 h4 = *(const u16x4*)(hid + base);
  f32x4 xi = *(const f32x4*)(x + base);
  f32x4 bd4 = *(const f32x4*)(bd + tid * 4);
  float v[4];
#pragma unroll
  for (int j = 0; j < 4; ++j) v[j] = bf2f(h4[j]) + xi[j] + bd4[j];
  float s = v[0] + v[1] + v[2] + v[3];
  float ss = v[0] * v[0] + v[1] * v[1] + v[2] * v[2] + v[3] * v[3];
#pragma unroll
  for (int o = 32; o > 0; o >>= 1) {
    s += __shfl_xor(s, o);
    ss += __shfl_xor(ss, o);
  }
  __shared__ float red[8];
  if (l == 0) { red[w] = s; red[w + 4] = ss; }
  __syncthreads();
  s = red[0] + red[1] + red[2] + red[3];
  ss = red[4] + red[5] + red[6] + red[7];
  const float mu = s * (1.0f / 1024.0f);
  const float var = ss * (1.0f / 1024.0f) - mu * mu;
  const float rstd = rsqrtf(var + 1e-12f);
  f32x4 g4 = *(const f32x4*)(g + tid * 4);
  f32x4 b4 = *(const f32x4*)(be + tid * 4);
  f32x4 o;
#pragma unroll
  for (int j = 0; j < 4; ++j) o[j] = (v[j] - mu) * rstd * g4[j] + b4[j];
  *(f32x4*)(out + base) = o;
}

// ---------------------------------------------------------------------------
extern "C" void kernel_launch(void* const* d_in, const int* in_sizes, int n_in,
                              void* d_out, int out_size, void* d_ws,
                              size_t ws_size, hipStream_t stream) {
  const float* X = (const float*)d_in[0];
  const float* Wq = (const float*)d_in[1];
  const float* bq = (const float*)d_in[2];
  const float* Wk = (const float*)d_in[3];
  const float* bk = (const float*)d_in[4];
  const float* Wv = (const float*)d_in[5];
  const float* bv = (const float*)d_in[6];
  const float* Wd = (const float*)d_in[7];
  const float* bd = (const float*)d_in[8];
  const float* gamma = (const float*)d_in[9];
  const float* beta = (const float*)d_in[10];
  float* out = (float*)d_out;

  char* ws = (char*)d_ws;
  u16* Xb = (u16*)(ws);                       // 64 MiB
  u16* Wt = (u16*)(ws + 67108864);            // 6 MiB  [3072][1024] bf16
  u16* eq = (u16*)(ws + 73400320);            // 64 MiB (-> qn in-place)
  u16* ek = (u16*)(ws + 140509184);           // 64 MiB (-> reused as hid)
  u16* vb = (u16*)(ws + 207618048);           // 64 MiB
  float* rk = (float*)(ws + 274726912);       // 2 MiB
  float* kvp = (float*)(ws + 276824064);      // 8 MiB (4 partials)
  u16* M2t = (u16*)(ws + 285212672);          // 16 MiB  [8][1024][1024] bf16
  // total ws use: 301,989,888 bytes

  k_cvt_x<<<16384, 256, 0, stream>>>(X, Xb);
  k_wt<<<dim3(4, 128, 3), 256, 0, stream>>>(Wq, Wk, Wv, Wt);
  k_gemm<0><<<dim3(256, 24), 256, 0, stream>>>(Xb, Wt, eq, ek, vb, bq, bk, bv);
  k_qnrk<<<8192, 256, 0, stream>>>(eq, ek, rk);
  k_kv<<<512, 256, 0, stream>>>(ek, vb, rk, kvp);
  k_m2<<<dim3(4, 16, 8), 256, 0, stream>>>(kvp, Wd, M2t);
  k_gemm<1><<<dim3(256, 8), 256, 0, stream>>>(eq, M2t, ek, nullptr, nullptr,
                                              nullptr, nullptr, nullptr);
  k_ln<<<32768, 256, 0, stream>>>(ek, X, bd, gamma, beta, out);
}

// Round 2
// 797.769 us; speedup vs baseline: 1.0207x; 1.0207x over previous
//
#include <hip/hip_runtime.h>
#include <cstdint>
#include <cstddef>

// Problem constants
#define B_ 8
#define S_ 4096
#define H_ 1024
#define NH_ 16
#define DH_ 64
#define MTOK 32768  // B_*S_

typedef unsigned short u16;
typedef __bf16 bf16x8 __attribute__((ext_vector_type(8)));
typedef u16 u16x8 __attribute__((ext_vector_type(8)));
typedef u16 u16x4 __attribute__((ext_vector_type(4)));
typedef float f32x4 __attribute__((ext_vector_type(4)));

#define DEVFN static __device__ __forceinline__

DEVFN float bf2f(u16 u) {
  union { uint32_t u; float f; } c; c.u = ((uint32_t)u) << 16; return c.f;
}
DEVFN u16 f2bf(float f) {
  union { float f; uint32_t u; } c; c.f = f;
  uint32_t r = c.u + 0x7fffu + ((c.u >> 16) & 1u);  // RNE
  return (u16)(r >> 16);
}
DEVFN void gload16(const void* g, void* lds_p) {
  __builtin_amdgcn_global_load_lds(
      (const __attribute__((address_space(1))) void*)g,
      (__attribute__((address_space(3))) void*)lds_p, 16, 0, 0);
}

#define FENCE asm volatile("" ::: "memory")
#define BAR do { FENCE; __builtin_amdgcn_s_barrier(); FENCE; } while (0)
#define WAITLGKM0 asm volatile("s_waitcnt lgkmcnt(0)" ::: "memory")

// ---------------------------------------------------------------------------
// Convert fp32 X -> bf16 Xb
__global__ __launch_bounds__(256) void k_cvt_x(const float* __restrict__ x,
                                               u16* __restrict__ xb) {
  const size_t i = ((size_t)blockIdx.x * 256 + threadIdx.x) * 8;
  f32x4 a = *(const f32x4*)(x + i);
  f32x4 b = *(const f32x4*)(x + i + 4);
  u16x8 o;
#pragma unroll
  for (int j = 0; j < 4; ++j) { o[j] = f2bf(a[j]); o[4 + j] = f2bf(b[j]); }
  *(u16x8*)(xb + i) = o;
}

// ---------------------------------------------------------------------------
// Wt[g*1024+n][k] = W_g[k][n]  (bf16, B^T layout for the GEMM)
__global__ __launch_bounds__(256) void k_wt(const float* __restrict__ Wq,
                                            const float* __restrict__ Wk,
                                            const float* __restrict__ Wv,
                                            u16* __restrict__ Wt) {
  const int n = blockIdx.x * 256 + threadIdx.x;  // 0..1023
  const int kc = blockIdx.y;                     // k-chunk of 8
  const int g = blockIdx.z;                      // 0..2
  const float* W = (g == 0) ? Wq : (g == 1) ? Wk : Wv;
  u16x8 o;
#pragma unroll
  for (int j = 0; j < 8; ++j) o[j] = f2bf(W[(size_t)(kc * 8 + j) * 1024 + n]);
  *(u16x8*)(Wt + ((size_t)(g * 1024 + n)) * 1024 + kc * 8) = o;
}

// ---------------------------------------------------------------------------
// 256x256 8-phase bf16 MFMA GEMM (T1+T2+T3+T4+T5), K=1024 (NT=16 K-tiles of 64).
// A[M,1024] row-major, Bt[N,1024] (B^T) row-major, M blocks = 128.
// 512 threads = 8 waves (2M x 4N); per-wave output 128x64.
// LDS 128KB: [buf2][A|B][half2][khalf2][row128][32 u16], st_16x32 swizzle
// (linear LDS dest for global_load_lds; pre-swizzled global source; XOR read).
// EPI=0: QKV epilogue (bias + elu for Q,K; col segment of N=3072)
// EPI=1: plain bf16 store (ctx GEMM, Bt indexed per-batch: Bt + batch*1M)
template <int EPI>
__global__ __launch_bounds__(512, 2) void k_gemm8(
    const u16* __restrict__ A, const u16* __restrict__ Bt,
    u16* __restrict__ o0, u16* __restrict__ o1, u16* __restrict__ o2,
    const float* __restrict__ bias0, const float* __restrict__ bias1,
    const float* __restrict__ bias2, int nblocks) {
  __shared__ __align__(16) char lds[131072];
  const int tid = threadIdx.x;
  const int w = tid >> 6, l = tid & 63;
  const int wm = w >> 2, wn = w & 3;

  // XCD-aware bijective swizzle (nblocks % 8 == 0), M-major within chunk
  const int chunk = nblocks >> 3;
  const int virt = ((int)blockIdx.x & 7) * chunk + ((int)blockIdx.x >> 3);
  const int bx = virt & 127;   // 128 M-blocks
  const int by = virt >> 7;
  const long row0 = (long)bx * 256;
  const long col0 = (long)by * 256;
  const u16* Bt2 = Bt + (EPI == 1 ? ((size_t)(row0 >> 12) << 20) : (size_t)0);

  // --- staging source pointers (per thread). Chunk c=(i*8+w)*64+l, i=khalf.
  // rS=(tid>>2)&127 local row, klo=(tid&3)*16 linear byte, source pre-swizzled.
  const int rS = (tid >> 2) & 127;
  const int koff = ((tid & 3) * 16) ^ ((tid & 32) ? 32 : 0);  // bytes
  const u16* srcA =
      A + (row0 + (rS & 63) + ((rS >> 6) << 7)) * 1024 + (koff >> 1);
  const u16* srcB =
      Bt2 + (col0 + (rS & 31) + ((rS >> 5) << 6)) * 1024 + (koff >> 1);

#define STAGE_A(buf, mh, t)                                              \
  do {                                                                   \
    const u16* s_ = srcA + (mh)*65536 + (size_t)(t)*64;                  \
    char* d_ = lds + (buf)*65536 + (mh)*16384 + w * 1024;                \
    gload16(s_, d_);                                                     \
    gload16(s_ + 32, d_ + 8192);                                         \
  } while (0)
#define STAGE_B(buf, bh, t)                                              \
  do {                                                                   \
    const u16* s_ = srcB + (bh)*32768 + (size_t)(t)*64;                  \
    char* d_ = lds + (buf)*65536 + 32768 + (bh)*16384 + w * 1024;        \
    gload16(s_, d_);                                                     \
    gload16(s_ + 32, d_ + 8192);                                         \
  } while (0)

  // --- LDS read addressing (swizzled): row r -> byte r*64 + (koff^((r&8)?32:0))
  const int rkoff = ((l >> 4) * 16) ^ ((l & 8) ? 32 : 0);
  const int aro = wm * 4096 + (l & 15) * 64 + rkoff;
  const int bro = wn * 2048 + (l & 15) * 64 + rkoff;

  bf16x8 a[4][2], b0r[2][2], b1r[2][2];
  f32x4 acc[8][4];
#pragma unroll
  for (int i = 0; i < 8; ++i)
#pragma unroll
    for (int j = 0; j < 4; ++j) acc[i][j] = (f32x4){0.f, 0.f, 0.f, 0.f};

#define LDA_(buf, mh)                                                    \
  do {                                                                   \
    const char* p_ = lds + (buf)*65536 + (mh)*16384 + aro;               \
    _Pragma("unroll") for (int mf = 0; mf < 4; ++mf)                     \
        _Pragma("unroll") for (int kh = 0; kh < 2; ++kh) a[mf][kh] =     \
        *(const bf16x8*)(p_ + mf * 1024 + kh * 8192);                    \
  } while (0)
#define LDB_(buf, nh, breg)                                              \
  do {                                                                   \
    const char* p_ = lds + (buf)*65536 + 32768 + (nh)*16384 + bro;       \
    _Pragma("unroll") for (int nf = 0; nf < 2; ++nf)                     \
        _Pragma("unroll") for (int kh = 0; kh < 2; ++kh) breg[nf][kh] =  \
        *(const bf16x8*)(p_ + nf * 1024 + kh * 8192);                    \
  } while (0)
#define MFMA_Q(mh, nh, breg)                                             \
  do {                                                                   \
    __builtin_amdgcn_s_setprio(1);                                       \
    _Pragma("unroll") for (int mf = 0; mf < 4; ++mf)                     \
        _Pragma("unroll") for (int nf = 0; nf < 2; ++nf)                 \
            _Pragma("unroll") for (int kh = 0; kh < 2; ++kh)             \
                acc[(mh)*4 + mf][(nh)*2 + nf] =                          \
        __builtin_amdgcn_mfma_f32_16x16x32_bf16(                         \
            a[mf][kh], breg[nf][kh], acc[(mh)*4 + mf][(nh)*2 + nf], 0,   \
            0, 0);                                                       \
    __builtin_amdgcn_s_setprio(0);                                       \
  } while (0)

  // Prologue: tile0 all 4 halves, tile1 first 3 halves; wait tile0; barrier.
  STAGE_A(0, 0, 0); STAGE_B(0, 0, 0); STAGE_A(0, 1, 0); STAGE_B(0, 1, 0);
  STAGE_A(1, 0, 1); STAGE_B(1, 0, 1); STAGE_A(1, 1, 1);
  asm volatile("s_waitcnt vmcnt(6)" ::: "memory");
  BAR;

#pragma unroll 2
  for (int t = 0; t < 16; ++t) {
    const int buf = t & 1;
    // ---- phase 1: Q00. reads A-h0(t), B-h0(t); stage B-h1(t+1)
    LDA_(buf, 0);
    LDB_(buf, 0, b0r);
    if (t + 1 < 16) STAGE_B(buf ^ 1, 1, t + 1);
    asm volatile("s_waitcnt lgkmcnt(8)" ::: "memory");
    BAR;
    WAITLGKM0;
    MFMA_Q(0, 0, b0r);
    BAR;
    // ---- phase 2: Q01. reads B-h1(t); stage A-h0(t+2)
    LDB_(buf, 1, b1r);
    if (t + 2 < 16) STAGE_A(buf, 0, t + 2);
    BAR;
    WAITLGKM0;
    MFMA_Q(0, 1, b1r);
    BAR;
    // ---- phase 3: Q10. reads A-h1(t); stage B-h0(t+2)
    LDA_(buf, 1);
    if (t + 2 < 16) STAGE_B(buf, 0, t + 2);
    BAR;
    WAITLGKM0;
    MFMA_Q(1, 0, b0r);
    BAR;
    // ---- phase 4: Q11. no reads; stage A-h1(t+2); counted vmcnt
    if (t + 2 < 16) {
      STAGE_A(buf, 1, t + 2);
      asm volatile("s_waitcnt vmcnt(6)" ::: "memory");
    } else {
      asm volatile("s_waitcnt vmcnt(0)" ::: "memory");
    }
    BAR;
    MFMA_Q(1, 1, b1r);
    BAR;
  }

  // Epilogue: frag row=(l>>4)*4+reg, col=l&15
  const int rb0 = (int)row0 + wm * 128 + ((l >> 4) << 2);
  if (EPI == 0) {
    const int seg = (int)(col0 >> 10);  // 0:Q 1:K 2:V (uniform per block)
    u16* outp = (seg == 0) ? o0 : (seg == 1) ? o1 : o2;
    const float* bias = (seg == 0) ? bias0 : (seg == 1) ? bias1 : bias2;
    const int clb = ((int)(col0 & 1023)) + wn * 64 + (l & 15);
#pragma unroll
    for (int Nf = 0; Nf < 4; ++Nf) {
      const float bv_ = bias[clb + Nf * 16];
#pragma unroll
      for (int Mf = 0; Mf < 8; ++Mf)
#pragma unroll
        for (int r = 0; r < 4; ++r) {
          float v = acc[Mf][Nf][r] + bv_;
          if (seg < 2) v = v > 0.f ? v : expm1f(v);  // elu
          outp[(size_t)(rb0 + Mf * 16 + r) * 1024 + clb + Nf * 16] = f2bf(v);
        }
    }
  } else {
    const int cb0 = (int)col0 + wn * 64 + (l & 15);
#pragma unroll
    for (int Mf = 0; Mf < 8; ++Mf)
#pragma unroll
      for (int Nf = 0; Nf < 4; ++Nf)
#pragma unroll
        for (int r = 0; r < 4; ++r)
          o0[(size_t)(rb0 + Mf * 16 + r) * 1024 + cb0 + Nf * 16] =
              f2bf(acc[Mf][Nf][r]);
  }
#undef STAGE_A
#undef STAGE_B
#undef LDA_
#undef LDB_
#undef MFMA_Q
}

// ---------------------------------------------------------------------------
// Per-(token,head) L2 norms: qn = eq/||eq|| in-place; rk = 1/||ek|| stored.
__global__ __launch_bounds__(256) void k_qnrk(u16* __restrict__ eq,
                                              const u16* __restrict__ ek,
                                              float* __restrict__ rk) {
  const int tid = threadIdx.x, w = tid >> 6, l = tid & 63;
  const long t = (long)blockIdx.x * 4 + w;
  const size_t base = (size_t)t * 1024 + (l >> 2) * 64 + (l & 3) * 16;
  u16x8 a = *(const u16x8*)(eq + base);
  u16x8 b = *(const u16x8*)(eq + base + 8);
  float f[16];
#pragma unroll
  for (int j = 0; j < 8; ++j) { f[j] = bf2f(a[j]); f[8 + j] = bf2f(b[j]); }
  float ss = 0.f;
#pragma unroll
  for (int j = 0; j < 16; ++j) ss += f[j] * f[j];
  ss += __shfl_xor(ss, 1);
  ss += __shfl_xor(ss, 2);
  const float rq = rsqrtf(ss);
  u16x8 oa, ob;
#pragma unroll
  for (int j = 0; j < 8; ++j) { oa[j] = f2bf(f[j] * rq); ob[j] = f2bf(f[8 + j] * rq); }
  *(u16x8*)(eq + base) = oa;
  *(u16x8*)(eq + base + 8) = ob;

  a = *(const u16x8*)(ek + base);
  b = *(const u16x8*)(ek + base + 8);
  float sk = 0.f;
#pragma unroll
  for (int j = 0; j < 8; ++j) {
    float x0 = bf2f(a[j]), x1 = bf2f(b[j]);
    sk += x0 * x0 + x1 * x1;
  }
  sk += __shfl_xor(sk, 1);
  sk += __shfl_xor(sk, 2);
  if ((l & 3) == 0) rk[t * 16 + (l >> 2)] = rsqrtf(sk);
}

// ---------------------------------------------------------------------------
// kv partials: kvp[sc][b][h][d][e] = sum over s-chunk of kn[s,d]*v[s,e]
__global__ __launch_bounds__(256) void k_kv(const u16* __restrict__ ek,
                                            const u16* __restrict__ vv,
                                            const float* __restrict__ rk,
                                            float* __restrict__ kvp) {
  __shared__ float kns[64][68];  // +4 pad: conflict-free staging & reads
  __shared__ float vs[64][68];
  const int tid = threadIdx.x;
  const int bid = blockIdx.x;  // sc + 4*(h + 16*b)
  const int sc = bid & 3, h = (bid >> 2) & 15, b = bid >> 6;
  const int d = tid >> 2, eg = tid & 3;
  float acc[16] = {};
  const long tbase = (long)b * 4096 + sc * 1024;
  for (int st = 0; st < 1024; st += 64) {
    const long t = tbase + st + (tid >> 2);
    const int q = tid & 3;
    const u16* ep = ek + (size_t)t * 1024 + h * 64 + q * 16;
    const u16* vp = vv + (size_t)t * 1024 + h * 64 + q * 16;
    u16x8 e0 = *(const u16x8*)ep, e1 = *(const u16x8*)(ep + 8);
    u16x8 v0 = *(const u16x8*)vp, v1 = *(const u16x8*)(vp + 8);
    const float rkv = rk[t * 16 + h];
    __syncthreads();  // previous tile fully consumed
#pragma unroll
    for (int j = 0; j < 8; ++j) {
      kns[tid >> 2][q * 16 + j] = bf2f(e0[j]) * rkv;
      kns[tid >> 2][q * 16 + 8 + j] = bf2f(e1[j]) * rkv;
      vs[tid >> 2][q * 16 + j] = bf2f(v0[j]);
      vs[tid >> 2][q * 16 + 8 + j] = bf2f(v1[j]);
    }
    __syncthreads();
    for (int s = 0; s < 64; ++s) {
      const float kn = kns[s][d];
      const f32x4* vr = (const f32x4*)&vs[s][eg * 16];
      f32x4 q0 = vr[0], q1 = vr[1], q2 = vr[2], q3 = vr[3];
#pragma unroll
      for (int j = 0; j < 4; ++j) {
        acc[j] += kn * q0[j];
        acc[4 + j] += kn * q1[j];
        acc[8 + j] += kn * q2[j];
        acc[12 + j] += kn * q3[j];
      }
    }
  }
  float* op = kvp + (((size_t)(sc * 8 + b) * 16 + h) * 64 + d) * 64 + eg * 16;
#pragma unroll
  for (int c = 0; c < 4; ++c) {
    f32x4 o = {acc[c * 4], acc[c * 4 + 1], acc[c * 4 + 2], acc[c * 4 + 3]};
    *(f32x4*)(op + c * 4) = o;
  }
}

// ---------------------------------------------------------------------------
// M2t[b][n][h*64+d] = (1/8) * sum_e kv[b,h][d][e] * Wd[h*64+e][n]   (bf16)
__global__ __launch_bounds__(256) void k_m2(const float* __restrict__ kvp,
                                            const float* __restrict__ Wd,
                                            u16* __restrict__ M2t) {
  const int tid = threadIdx.x;
  const int nb = blockIdx.x, h = blockIdx.y, b = blockIdx.z;
  const int d = tid >> 2, eg = tid & 3;
  const size_t kbase = (((size_t)(b * 16 + h)) * 64 + d) * 64 + eg * 16;
  float kvr[16];
#pragma unroll
  for (int c = 0; c < 4; ++c) {
    f32x4 s = *(const f32x4*)(kvp + kbase + c * 4);
#pragma unroll
    for (int sc = 1; sc < 4; ++sc)
      s += *(const f32x4*)(kvp + (size_t)sc * 524288 + kbase + c * 4);
#pragma unroll
    for (int j = 0; j < 4; ++j) kvr[c * 4 + j] = s[j];
  }
  const float* wcol = Wd + ((size_t)h * 64 + eg * 16) * 1024;
  for (int n = nb * 256; n < nb * 256 + 256; ++n) {
    float p = 0.f;
#pragma unroll
    for (int i = 0; i < 16; ++i) p += kvr[i] * wcol[(size_t)i * 1024 + n];
    p += __shfl_xor(p, 1);
    p += __shfl_xor(p, 2);
    if (eg == 0)
      M2t[((size_t)b * 1024 + n) * 1024 + h * 64 + d] = f2bf(p * 0.125f);
  }
}

// ---------------------------------------------------------------------------
// LayerNorm(hid + bd + x) * gamma + beta  -> fp32 out
__global__ __launch_bounds__(256) void k_ln(const u16* __restrict__ hid,
                                            const float* __restrict__ x,
                                            const float* __restrict__ bd,
                                            const float* __restrict__ g,
                                            const float* __restrict__ be,
                                            float* __restrict__ out) {
  const int tid = threadIdx.x, w = tid >> 6, l = tid & 63;
  const size_t base = (size_t)blockIdx.x * 1024 + tid * 4;
  u16x4 h4 = *(const u16x4*)(hid + base);
  f32x4 xi = *(const f32x4*)(x + base);
  f32x4 bd4 = *(const f32x4*)(bd + tid * 4);
  float v[4];
#pragma unroll
  for (int j = 0; j < 4; ++j) v[j] = bf2f(h4[j]) + xi[j] + bd4[j];
  float s = v[0] + v[1] + v[2] + v[3];
  float ss = v[0] * v[0] + v[1] * v[1] + v[2] * v[2] + v[3] * v[3];
#pragma unroll
  for (int o = 32; o > 0; o >>= 1) {
    s += __shfl_xor(s, o);
    ss += __shfl_xor(ss, o);
  }
  __shared__ float red[8];
  if (l == 0) { red[w] = s; red[w + 4] = ss; }
  __syncthreads();
  s = red[0] + red[1] + red[2] + red[3];
  ss = red[4] + red[5] + red[6] + red[7];
  const float mu = s * (1.0f / 1024.0f);
  const float var = ss * (1.0f / 1024.0f) - mu * mu;
  const float rstd = rsqrtf(var + 1e-12f);
  f32x4 g4 = *(const f32x4*)(g + tid * 4);
  f32x4 b4 = *(const f32x4*)(be + tid * 4);
  f32x4 o;
#pragma unroll
  for (int j = 0; j < 4; ++j) o[j] = (v[j] - mu) * rstd * g4[j] + b4[j];
  *(f32x4*)(out + base) = o;
}

// ---------------------------------------------------------------------------
extern "C" void kernel_launch(void* const* d_in, const int* in_sizes, int n_in,
                              void* d_out, int out_size, void* d_ws,
                              size_t ws_size, hipStream_t stream) {
  const float* X = (const float*)d_in[0];
  const float* Wq = (const float*)d_in[1];
  const float* bq = (const float*)d_in[2];
  const float* Wk = (const float*)d_in[3];
  const float* bk = (const float*)d_in[4];
  const float* Wv = (const float*)d_in[5];
  const float* bv = (const float*)d_in[6];
  const float* Wd = (const float*)d_in[7];
  const float* bd = (const float*)d_in[8];
  const float* gamma = (const float*)d_in[9];
  const float* beta = (const float*)d_in[10];
  float* out = (float*)d_out;

  char* ws = (char*)d_ws;
  u16* Xb = (u16*)(ws);                       // 64 MiB
  u16* Wt = (u16*)(ws + 67108864);            // 6 MiB  [3072][1024] bf16
  u16* eq = (u16*)(ws + 73400320);            // 64 MiB (-> qn in-place)
  u16* ek = (u16*)(ws + 140509184);           // 64 MiB (-> reused as hid)
  u16* vb = (u16*)(ws + 207618048);           // 64 MiB
  float* rk = (float*)(ws + 274726912);       // 2 MiB
  float* kvp = (float*)(ws + 276824064);      // 8 MiB (4 partials)
  u16* M2t = (u16*)(ws + 285212672);          // 16 MiB  [8][1024][1024] bf16
  // total ws use: 301,989,888 bytes

  k_cvt_x<<<16384, 256, 0, stream>>>(X, Xb);
  k_wt<<<dim3(4, 128, 3), 256, 0, stream>>>(Wq, Wk, Wv, Wt);
  k_gemm8<0><<<1536, 512, 0, stream>>>(Xb, Wt, eq, ek, vb, bq, bk, bv, 1536);
  k_qnrk<<<8192, 256, 0, stream>>>(eq, ek, rk);
  k_kv<<<512, 256, 0, stream>>>(ek, vb, rk, kvp);
  k_m2<<<dim3(4, 16, 8), 256, 0, stream>>>(kvp, Wd, M2t);
  k_gemm8<1><<<512, 512, 0, stream>>>(eq, M2t, ek, nullptr, nullptr, nullptr,
                                      nullptr, nullptr, 512);
  k_ln<<<32768, 256, 0, stream>>>(ek, X, bd, gamma, beta, out);
}

// Round 3
// 781.892 us; speedup vs baseline: 1.0414x; 1.0203x over previous
//
#include <hip/hip_runtime.h>
#include <cstdint>
#include <cstddef>

// Problem constants
#define B_ 8
#define S_ 4096
#define H_ 1024
#define NH_ 16
#define DH_ 64
#define MTOK 32768  // B_*S_

typedef unsigned short u16;
typedef __bf16 bf16x8 __attribute__((ext_vector_type(8)));
typedef u16 u16x8 __attribute__((ext_vector_type(8)));
typedef u16 u16x4 __attribute__((ext_vector_type(4)));
typedef float f32x4 __attribute__((ext_vector_type(4)));

#define DEVFN static __device__ __forceinline__

DEVFN float bf2f(u16 u) {
  union { uint32_t u; float f; } c; c.u = ((uint32_t)u) << 16; return c.f;
}
DEVFN u16 f2bf(float f) {
  union { float f; uint32_t u; } c; c.f = f;
  uint32_t r = c.u + 0x7fffu + ((c.u >> 16) & 1u);  // RNE
  return (u16)(r >> 16);
}
DEVFN void gload16(const void* g, void* lds_p) {
  __builtin_amdgcn_global_load_lds(
      (const __attribute__((address_space(1))) void*)g,
      (__attribute__((address_space(3))) void*)lds_p, 16, 0, 0);
}

#define FENCE asm volatile("" ::: "memory")
#define BAR do { FENCE; __builtin_amdgcn_s_barrier(); FENCE; } while (0)
#define WAITLGKM0 asm volatile("s_waitcnt lgkmcnt(0)" ::: "memory")
#define SCHEDBAR __builtin_amdgcn_sched_barrier(0)

// ---------------------------------------------------------------------------
// Convert fp32 X -> bf16 Xb
__global__ __launch_bounds__(256) void k_cvt_x(const float* __restrict__ x,
                                               u16* __restrict__ xb) {
  const size_t i = ((size_t)blockIdx.x * 256 + threadIdx.x) * 8;
  f32x4 a = *(const f32x4*)(x + i);
  f32x4 b = *(const f32x4*)(x + i + 4);
  u16x8 o;
#pragma unroll
  for (int j = 0; j < 4; ++j) { o[j] = f2bf(a[j]); o[4 + j] = f2bf(b[j]); }
  *(u16x8*)(xb + i) = o;
}

// ---------------------------------------------------------------------------
// Wt[g*1024+n][k] = W_g[k][n]  (bf16, B^T layout for the GEMM)
__global__ __launch_bounds__(256) void k_wt(const float* __restrict__ Wq,
                                            const float* __restrict__ Wk,
                                            const float* __restrict__ Wv,
                                            u16* __restrict__ Wt) {
  const int n = blockIdx.x * 256 + threadIdx.x;  // 0..1023
  const int kc = blockIdx.y;                     // k-chunk of 8
  const int g = blockIdx.z;                      // 0..2
  const float* W = (g == 0) ? Wq : (g == 1) ? Wk : Wv;
  u16x8 o;
#pragma unroll
  for (int j = 0; j < 8; ++j) o[j] = f2bf(W[(size_t)(kc * 8 + j) * 1024 + n]);
  *(u16x8*)(Wt + ((size_t)(g * 1024 + n)) * 1024 + kc * 8) = o;
}

// ---------------------------------------------------------------------------
// 256x256 8-phase bf16 MFMA GEMM, K=1024 (16 K-tiles of 64).
// A[M,1024] row-major, Bt[N,1024] (B^T) row-major, 128 M-blocks.
// 512 threads = 8 waves (2M x 4N); per-wave output 128x64.
// LDS 128KB: [buf2][A|B][half2][khalf2][row128][32 u16], st_16x32 swizzle
// (linear LDS dest for global_load_lds; pre-swizzled global source; XOR read).
// Epilogue: C staged through LDS (bf16, XOR col-group swizzle) -> coalesced
// dwordx4 stores (512B contiguous runs).
// EPI=0: QKV (bias + elu for Q,K; col segment of N=3072), grid 1536.
// EPI=1: plain store (ctx GEMM, Bt per-batch: Bt + batch*1M), grid 512.
template <int EPI>
__global__ __launch_bounds__(512, 2) void k_gemm8(
    const u16* __restrict__ A, const u16* __restrict__ Bt,
    u16* __restrict__ o0, u16* __restrict__ o1, u16* __restrict__ o2,
    const float* __restrict__ bias0, const float* __restrict__ bias1,
    const float* __restrict__ bias2) {
  __shared__ __align__(16) char lds[131072];
  const int tid = threadIdx.x;
  const int w = tid >> 6, l = tid & 63;
  const int wm = w >> 2, wn = w & 3;

  // bx-aligned XCD swizzle: at step i, all 8 XCDs process the SAME bx so each
  // A-row-panel is HBM-fetched once and L3-served to the other 7 XCDs.
  const int bid = (int)blockIdx.x;
  const int xcd = bid & 7, ii = bid >> 3;
  int bx, by;
  if (EPI == 0) {  // 1536 blocks: by 0..11
    if (ii < 128) { by = xcd; bx = ii; }
    else { by = 8 + (xcd >> 1); bx = (ii - 128) + ((xcd & 1) << 6); }
  } else {         // 512 blocks: by 0..3
    by = xcd >> 1; bx = ii + ((xcd & 1) << 6);
  }
  const long row0 = (long)bx * 256;
  const long col0 = (long)by * 256;
  const u16* Bt2 = Bt + (EPI == 1 ? ((size_t)(row0 >> 12) << 20) : (size_t)0);

  // --- staging source pointers (per thread); source pre-swizzled (st_16x32).
  const int rS = (tid >> 2) & 127;
  const int koff = ((tid & 3) * 16) ^ ((tid & 32) ? 32 : 0);  // bytes
  const u16* srcA =
      A + (row0 + (rS & 63) + ((rS >> 6) << 7)) * 1024 + (koff >> 1);
  const u16* srcB =
      Bt2 + (col0 + (rS & 31) + ((rS >> 5) << 6)) * 1024 + (koff >> 1);

#define STAGE_A(buf, mh, t)                                              \
  do {                                                                   \
    const u16* s_ = srcA + (mh)*65536 + (size_t)(t)*64;                  \
    char* d_ = lds + (buf)*65536 + (mh)*16384 + w * 1024;                \
    gload16(s_, d_);                                                     \
    gload16(s_ + 32, d_ + 8192);                                         \
  } while (0)
#define STAGE_B(buf, bh, t)                                              \
  do {                                                                   \
    const u16* s_ = srcB + (bh)*32768 + (size_t)(t)*64;                  \
    char* d_ = lds + (buf)*65536 + 32768 + (bh)*16384 + w * 1024;        \
    gload16(s_, d_);                                                     \
    gload16(s_ + 32, d_ + 8192);                                         \
  } while (0)

  // --- LDS read addressing (swizzled): row r -> byte r*64 + (kbyte^((r&8)?32:0))
  const int rkoff = ((l >> 4) * 16) ^ ((l & 8) ? 32 : 0);
  const int aro = wm * 4096 + (l & 15) * 64 + rkoff;
  const int bro = wn * 2048 + (l & 15) * 64 + rkoff;

  bf16x8 a[4][2], b0r[2][2], b1r[2][2];
  f32x4 acc[8][4];
#pragma unroll
  for (int i = 0; i < 8; ++i)
#pragma unroll
    for (int j = 0; j < 4; ++j) acc[i][j] = (f32x4){0.f, 0.f, 0.f, 0.f};

#define LDA_(buf, mh)                                                    \
  do {                                                                   \
    const char* p_ = lds + (buf)*65536 + (mh)*16384 + aro;               \
    _Pragma("unroll") for (int mf = 0; mf < 4; ++mf)                     \
        _Pragma("unroll") for (int kh = 0; kh < 2; ++kh) a[mf][kh] =     \
        *(const bf16x8*)(p_ + mf * 1024 + kh * 8192);                    \
  } while (0)
#define LDB_(buf, nh, breg)                                              \
  do {                                                                   \
    const char* p_ = lds + (buf)*65536 + 32768 + (nh)*16384 + bro;       \
    _Pragma("unroll") for (int nf = 0; nf < 2; ++nf)                     \
        _Pragma("unroll") for (int kh = 0; kh < 2; ++kh) breg[nf][kh] =  \
        *(const bf16x8*)(p_ + nf * 1024 + kh * 8192);                    \
  } while (0)
#define MFMA_Q(mh, nh, breg)                                             \
  do {                                                                   \
    SCHEDBAR;                                                            \
    __builtin_amdgcn_s_setprio(1);                                       \
    _Pragma("unroll") for (int mf = 0; mf < 4; ++mf)                     \
        _Pragma("unroll") for (int nf = 0; nf < 2; ++nf)                 \
            _Pragma("unroll") for (int kh = 0; kh < 2; ++kh)             \
                acc[(mh)*4 + mf][(nh)*2 + nf] =                          \
        __builtin_amdgcn_mfma_f32_16x16x32_bf16(                         \
            a[mf][kh], breg[nf][kh], acc[(mh)*4 + mf][(nh)*2 + nf], 0,   \
            0, 0);                                                       \
    __builtin_amdgcn_s_setprio(0);                                       \
    SCHEDBAR;                                                            \
  } while (0)

  // Prologue: tile0 all 4 halves, tile1 first 3 halves; wait tile0; barrier.
  STAGE_A(0, 0, 0); STAGE_B(0, 0, 0); STAGE_A(0, 1, 0); STAGE_B(0, 1, 0);
  STAGE_A(1, 0, 1); STAGE_B(1, 0, 1); STAGE_A(1, 1, 1);
  asm volatile("s_waitcnt vmcnt(6)" ::: "memory");
  BAR;

#pragma unroll 2
  for (int t = 0; t < 16; ++t) {
    const int buf = t & 1;
    // ---- phase 1: Q00. reads A-h0(t), B-h0(t); stage B-h1(t+1)
    LDA_(buf, 0);
    LDB_(buf, 0, b0r);
    if (t + 1 < 16) STAGE_B(buf ^ 1, 1, t + 1);
    asm volatile("s_waitcnt lgkmcnt(8)" ::: "memory");
    BAR;
    WAITLGKM0;
    MFMA_Q(0, 0, b0r);
    BAR;
    // ---- phase 2: Q01. reads B-h1(t); stage A-h0(t+2)
    LDB_(buf, 1, b1r);
    if (t + 2 < 16) STAGE_A(buf, 0, t + 2);
    BAR;
    WAITLGKM0;
    MFMA_Q(0, 1, b1r);
    BAR;
    // ---- phase 3: Q10. reads A-h1(t); stage B-h0(t+2)
    LDA_(buf, 1);
    if (t + 2 < 16) STAGE_B(buf, 0, t + 2);
    BAR;
    WAITLGKM0;
    MFMA_Q(1, 0, b0r);
    BAR;
    // ---- phase 4: Q11. no reads; stage A-h1(t+2); counted vmcnt
    if (t + 2 < 16) {
      STAGE_A(buf, 1, t + 2);
      asm volatile("s_waitcnt vmcnt(6)" ::: "memory");
    } else {
      asm volatile("s_waitcnt vmcnt(0)" ::: "memory");
    }
    BAR;
    MFMA_Q(1, 1, b1r);
    BAR;
  }

  // ---- Epilogue: stage C (bf16) into LDS, then coalesced dwordx4 stores.
  // LDS C layout: u16[256][256] with col-group XOR swizzle:
  //   u16 index = row*256 + (cg ^ (row&7))*16 + (col&15),  cg = col>>4.
  u16* cl = (u16*)lds;
  const int seg = (EPI == 0) ? (int)(col0 >> 10) : 0;  // 0:Q 1:K 2:V
  const float* bias =
      (EPI == 0) ? ((seg == 0) ? bias0 : (seg == 1) ? bias1 : bias2) : nullptr;
  const int clb = (EPI == 0) ? ((int)(col0 & 1023) + wn * 64 + (l & 15)) : 0;
  const int rbase = wm * 128 + ((l >> 4) << 2);
  const int cgrp0 = wn * 4;
#pragma unroll
  for (int Nf = 0; Nf < 4; ++Nf) {
    const float bv_ = (EPI == 0) ? bias[clb + Nf * 16] : 0.f;
#pragma unroll
    for (int Mf = 0; Mf < 8; ++Mf)
#pragma unroll
      for (int r = 0; r < 4; ++r) {
        const int row = rbase + Mf * 16 + r;
        float v = acc[Mf][Nf][r];
        if (EPI == 0) {
          v += bv_;
          if (seg < 2) v = v > 0.f ? v : expm1f(v);  // elu
        }
        cl[row * 256 + ((cgrp0 + Nf) ^ (row & 7)) * 16 + (l & 15)] = f2bf(v);
      }
  }
  WAITLGKM0;  // own ds_writes done
  BAR;        // all waves' C visible
  // Read back row-linear: store i covers rows w*32+i*2+{0,1}; lanes 0..31 ->
  // row r0 (512B contiguous), lanes 32..63 -> row r0+1.
  u16* outp = (EPI == 0) ? ((seg == 0) ? o0 : (seg == 1) ? o1 : o2) : o0;
  const int colseg = (EPI == 0) ? (int)(col0 & 1023) : (int)col0;
  const int cg = (l & 31) >> 1;           // 32B col-group
  const int lo = (l & 1) << 4;            // byte within group
#pragma unroll
  for (int i = 0; i < 16; ++i) {
    const int row = w * 32 + i * 2 + (l >> 5);
    const u16x8 val = *(const u16x8*)((const char*)cl + row * 512 +
                                      ((cg ^ (row & 7)) << 5) + lo);
    *(u16x8*)(outp + (size_t)(row0 + row) * 1024 + colseg + (l & 31) * 8) = val;
  }
#undef STAGE_A
#undef STAGE_B
#undef LDA_
#undef LDB_
#undef MFMA_Q
}

// ---------------------------------------------------------------------------
// Per-(token,head) L2 norms: qn = eq/||eq|| in-place; rk = 1/||ek|| stored.
__global__ __launch_bounds__(256) void k_qnrk(u16* __restrict__ eq,
                                              const u16* __restrict__ ek,
                                              float* __restrict__ rk) {
  const int tid = threadIdx.x, w = tid >> 6, l = tid & 63;
  const long t = (long)blockIdx.x * 4 + w;
  const size_t base = (size_t)t * 1024 + (l >> 2) * 64 + (l & 3) * 16;
  u16x8 a = *(const u16x8*)(eq + base);
  u16x8 b = *(const u16x8*)(eq + base + 8);
  float f[16];
#pragma unroll
  for (int j = 0; j < 8; ++j) { f[j] = bf2f(a[j]); f[8 + j] = bf2f(b[j]); }
  float ss = 0.f;
#pragma unroll
  for (int j = 0; j < 16; ++j) ss += f[j] * f[j];
  ss += __shfl_xor(ss, 1);
  ss += __shfl_xor(ss, 2);
  const float rq = rsqrtf(ss);
  u16x8 oa, ob;
#pragma unroll
  for (int j = 0; j < 8; ++j) { oa[j] = f2bf(f[j] * rq); ob[j] = f2bf(f[8 + j] * rq); }
  *(u16x8*)(eq + base) = oa;
  *(u16x8*)(eq + base + 8) = ob;

  a = *(const u16x8*)(ek + base);
  b = *(const u16x8*)(ek + base + 8);
  float sk = 0.f;
#pragma unroll
  for (int j = 0; j < 8; ++j) {
    float x0 = bf2f(a[j]), x1 = bf2f(b[j]);
    sk += x0 * x0 + x1 * x1;
  }
  sk += __shfl_xor(sk, 1);
  sk += __shfl_xor(sk, 2);
  if ((l & 3) == 0) rk[t * 16 + (l >> 2)] = rsqrtf(sk);
}

// ---------------------------------------------------------------------------
// kv partials: kvp[sc][b][h][d][e] = sum over s-chunk of kn[s,d]*v[s,e]
__global__ __launch_bounds__(256) void k_kv(const u16* __restrict__ ek,
                                            const u16* __restrict__ vv,
                                            const float* __restrict__ rk,
                                            float* __restrict__ kvp) {
  __shared__ float kns[64][68];  // +4 pad: conflict-free staging & reads
  __shared__ float vs[64][68];
  const int tid = threadIdx.x;
  const int bid = blockIdx.x;  // sc + 4*(h + 16*b)
  const int sc = bid & 3, h = (bid >> 2) & 15, b = bid >> 6;
  const int d = tid >> 2, eg = tid & 3;
  float acc[16] = {};
  const long tbase = (long)b * 4096 + sc * 1024;
  for (int st = 0; st < 1024; st += 64) {
    const long t = tbase + st + (tid >> 2);
    const int q = tid & 3;
    const u16* ep = ek + (size_t)t * 1024 + h * 64 + q * 16;
    const u16* vp = vv + (size_t)t * 1024 + h * 64 + q * 16;
    u16x8 e0 = *(const u16x8*)ep, e1 = *(const u16x8*)(ep + 8);
    u16x8 v0 = *(const u16x8*)vp, v1 = *(const u16x8*)(vp + 8);
    const float rkv = rk[t * 16 + h];
    __syncthreads();  // previous tile fully consumed
#pragma unroll
    for (int j = 0; j < 8; ++j) {
      kns[tid >> 2][q * 16 + j] = bf2f(e0[j]) * rkv;
      kns[tid >> 2][q * 16 + 8 + j] = bf2f(e1[j]) * rkv;
      vs[tid >> 2][q * 16 + j] = bf2f(v0[j]);
      vs[tid >> 2][q * 16 + 8 + j] = bf2f(v1[j]);
    }
    __syncthreads();
    for (int s = 0; s < 64; ++s) {
      const float kn = kns[s][d];
      const f32x4* vr = (const f32x4*)&vs[s][eg * 16];
      f32x4 q0 = vr[0], q1 = vr[1], q2 = vr[2], q3 = vr[3];
#pragma unroll
      for (int j = 0; j < 4; ++j) {
        acc[j] += kn * q0[j];
        acc[4 + j] += kn * q1[j];
        acc[8 + j] += kn * q2[j];
        acc[12 + j] += kn * q3[j];
      }
    }
  }
  float* op = kvp + (((size_t)(sc * 8 + b) * 16 + h) * 64 + d) * 64 + eg * 16;
#pragma unroll
  for (int c = 0; c < 4; ++c) {
    f32x4 o = {acc[c * 4], acc[c * 4 + 1], acc[c * 4 + 2], acc[c * 4 + 3]};
    *(f32x4*)(op + c * 4) = o;
  }
}

// ---------------------------------------------------------------------------
// M2t[b][n][h*64+d] = (1/8) * sum_e kv[b,h][d][e] * Wd[h*64+e][n]   (bf16)
__global__ __launch_bounds__(256) void k_m2(const float* __restrict__ kvp,
                                            const float* __restrict__ Wd,
                                            u16* __restrict__ M2t) {
  const int tid = threadIdx.x;
  const int nb = blockIdx.x, h = blockIdx.y, b = blockIdx.z;
  const int d = tid >> 2, eg = tid & 3;
  const size_t kbase = (((size_t)(b * 16 + h)) * 64 + d) * 64 + eg * 16;
  float kvr[16];
#pragma unroll
  for (int c = 0; c < 4; ++c) {
    f32x4 s = *(const f32x4*)(kvp + kbase + c * 4);
#pragma unroll
    for (int sc = 1; sc < 4; ++sc)
      s += *(const f32x4*)(kvp + (size_t)sc * 524288 + kbase + c * 4);
#pragma unroll
    for (int j = 0; j < 4; ++j) kvr[c * 4 + j] = s[j];
  }
  const float* wcol = Wd + ((size_t)h * 64 + eg * 16) * 1024;
  for (int n = nb * 256; n < nb * 256 + 256; ++n) {
    float p = 0.f;
#pragma unroll
    for (int i = 0; i < 16; ++i) p += kvr[i] * wcol[(size_t)i * 1024 + n];
    p += __shfl_xor(p, 1);
    p += __shfl_xor(p, 2);
    if (eg == 0)
      M2t[((size_t)b * 1024 + n) * 1024 + h * 64 + d] = f2bf(p * 0.125f);
  }
}

// ---------------------------------------------------------------------------
// LayerNorm(hid + bd + x) * gamma + beta  -> fp32 out
__global__ __launch_bounds__(256) void k_ln(const u16* __restrict__ hid,
                                            const float* __restrict__ x,
                                            const float* __restrict__ bd,
                                            const float* __restrict__ g,
                                            const float* __restrict__ be,
                                            float* __restrict__ out) {
  const int tid = threadIdx.x, w = tid >> 6, l = tid & 63;
  const size_t base = (size_t)blockIdx.x * 1024 + tid * 4;
  u16x4 h4 = *(const u16x4*)(hid + base);
  f32x4 xi = *(const f32x4*)(x + base);
  f32x4 bd4 = *(const f32x4*)(bd + tid * 4);
  float v[4];
#pragma unroll
  for (int j = 0; j < 4; ++j) v[j] = bf2f(h4[j]) + xi[j] + bd4[j];
  float s = v[0] + v[1] + v[2] + v[3];
  float ss = v[0] * v[0] + v[1] * v[1] + v[2] * v[2] + v[3] * v[3];
#pragma unroll
  for (int o = 32; o > 0; o >>= 1) {
    s += __shfl_xor(s, o);
    ss += __shfl_xor(ss, o);
  }
  __shared__ float red[8];
  if (l == 0) { red[w] = s; red[w + 4] = ss; }
  __syncthreads();
  s = red[0] + red[1] + red[2] + red[3];
  ss = red[4] + red[5] + red[6] + red[7];
  const float mu = s * (1.0f / 1024.0f);
  const float var = ss * (1.0f / 1024.0f) - mu * mu;
  const float rstd = rsqrtf(var + 1e-12f);
  f32x4 g4 = *(const f32x4*)(g + tid * 4);
  f32x4 b4 = *(const f32x4*)(be + tid * 4);
  f32x4 o;
#pragma unroll
  for (int j = 0; j < 4; ++j) o[j] = (v[j] - mu) * rstd * g4[j] + b4[j];
  *(f32x4*)(out + base) = o;
}

// ---------------------------------------------------------------------------
extern "C" void kernel_launch(void* const* d_in, const int* in_sizes, int n_in,
                              void* d_out, int out_size, void* d_ws,
                              size_t ws_size, hipStream_t stream) {
  const float* X = (const float*)d_in[0];
  const float* Wq = (const float*)d_in[1];
  const float* bq = (const float*)d_in[2];
  const float* Wk = (const float*)d_in[3];
  const float* bk = (const float*)d_in[4];
  const float* Wv = (const float*)d_in[5];
  const float* bv = (const float*)d_in[6];
  const float* Wd = (const float*)d_in[7];
  const float* bd = (const float*)d_in[8];
  const float* gamma = (const float*)d_in[9];
  const float* beta = (const float*)d_in[10];
  float* out = (float*)d_out;

  char* ws = (char*)d_ws;
  u16* Xb = (u16*)(ws);                       // 64 MiB
  u16* Wt = (u16*)(ws + 67108864);            // 6 MiB  [3072][1024] bf16
  u16* eq = (u16*)(ws + 73400320);            // 64 MiB (-> qn in-place)
  u16* ek = (u16*)(ws + 140509184);           // 64 MiB (-> reused as hid)
  u16* vb = (u16*)(ws + 207618048);           // 64 MiB
  float* rk = (float*)(ws + 274726912);       // 2 MiB
  float* kvp = (float*)(ws + 276824064);      // 8 MiB (4 partials)
  u16* M2t = (u16*)(ws + 285212672);          // 16 MiB  [8][1024][1024] bf16
  // total ws use: 301,989,888 bytes

  k_cvt_x<<<16384, 256, 0, stream>>>(X, Xb);
  k_wt<<<dim3(4, 128, 3), 256, 0, stream>>>(Wq, Wk, Wv, Wt);
  k_gemm8<0><<<1536, 512, 0, stream>>>(Xb, Wt, eq, ek, vb, bq, bk, bv);
  k_qnrk<<<8192, 256, 0, stream>>>(eq, ek, rk);
  k_kv<<<512, 256, 0, stream>>>(ek, vb, rk, kvp);
  k_m2<<<dim3(4, 16, 8), 256, 0, stream>>>(kvp, Wd, M2t);
  k_gemm8<1><<<512, 512, 0, stream>>>(eq, M2t, ek, nullptr, nullptr, nullptr,
                                      nullptr, nullptr);
  k_ln<<<32768, 256, 0, stream>>>(ek, X, bd, gamma, beta, out);
}

// Round 4
// 757.382 us; speedup vs baseline: 1.0751x; 1.0324x over previous
//
#include <hip/hip_runtime.h>
#include <cstdint>
#include <cstddef>

// Problem constants
#define B_ 8
#define S_ 4096
#define H_ 1024
#define NH_ 16
#define DH_ 64
#define MTOK 32768  // B_*S_

typedef unsigned short u16;
typedef __bf16 bf16x8 __attribute__((ext_vector_type(8)));
typedef u16 u16x8 __attribute__((ext_vector_type(8)));
typedef u16 u16x4 __attribute__((ext_vector_type(4)));
typedef float f32x4 __attribute__((ext_vector_type(4)));

#define DEVFN static __device__ __forceinline__

DEVFN float bf2f(u16 u) {
  union { uint32_t u; float f; } c; c.u = ((uint32_t)u) << 16; return c.f;
}
DEVFN u16 f2bf(float f) {
  union { float f; uint32_t u; } c; c.f = f;
  uint32_t r = c.u + 0x7fffu + ((c.u >> 16) & 1u);  // RNE
  return (u16)(r >> 16);
}
DEVFN void gload16(const void* g, void* lds_p) {
  __builtin_amdgcn_global_load_lds(
      (const __attribute__((address_space(1))) void*)g,
      (__attribute__((address_space(3))) void*)lds_p, 16, 0, 0);
}

#define FENCE asm volatile("" ::: "memory")
#define BAR do { FENCE; __builtin_amdgcn_s_barrier(); FENCE; } while (0)
#define WAITLGKM0 asm volatile("s_waitcnt lgkmcnt(0)" ::: "memory")
#define SCHEDBAR __builtin_amdgcn_sched_barrier(0)

// ---------------------------------------------------------------------------
// Convert fp32 X -> bf16 Xb
__global__ __launch_bounds__(256) void k_cvt_x(const float* __restrict__ x,
                                               u16* __restrict__ xb) {
  const size_t i = ((size_t)blockIdx.x * 256 + threadIdx.x) * 8;
  f32x4 a = *(const f32x4*)(x + i);
  f32x4 b = *(const f32x4*)(x + i + 4);
  u16x8 o;
#pragma unroll
  for (int j = 0; j < 4; ++j) { o[j] = f2bf(a[j]); o[4 + j] = f2bf(b[j]); }
  *(u16x8*)(xb + i) = o;
}

// ---------------------------------------------------------------------------
// Wt[g*1024+n][k] = W_g[k][n]  (bf16, B^T layout for the GEMM)
__global__ __launch_bounds__(256) void k_wt(const float* __restrict__ Wq,
                                            const float* __restrict__ Wk,
                                            const float* __restrict__ Wv,
                                            u16* __restrict__ Wt) {
  const int n = blockIdx.x * 256 + threadIdx.x;  // 0..1023
  const int kc = blockIdx.y;                     // k-chunk of 8
  const int g = blockIdx.z;                      // 0..2
  const float* W = (g == 0) ? Wq : (g == 1) ? Wk : Wv;
  u16x8 o;
#pragma unroll
  for (int j = 0; j < 8; ++j) o[j] = f2bf(W[(size_t)(kc * 8 + j) * 1024 + n]);
  *(u16x8*)(Wt + ((size_t)(g * 1024 + n)) * 1024 + kc * 8) = o;
}

// ---------------------------------------------------------------------------
// 256x256 8-phase bf16 MFMA GEMM, K=1024 (16 K-tiles of 64).
// A[M,1024] row-major, Bt[N,1024] (B^T) row-major, 128 M-blocks.
// 512 threads = 8 waves (2M x 4N); per-wave output 128x64.
// LDS 128KB: [buf2][A|B][half2][khalf2][row128][32 u16], st_16x32 swizzle
// (linear LDS dest for global_load_lds; pre-swizzled global source; XOR read).
// Grid order gives L2-level A-panel sharing: each XCD's ~32 concurrent blocks
// span 8 bx x 4 by (active set A 4MB + B 2MB, ~L2-fit).
// Epilogue: C staged through LDS (bf16, XOR col-group swizzle) -> coalesced
// dwordx4 stores; EPI=0 fuses per-(row,head) L2 normalization for Q/K segs.
// EPI=0: QKV (bias + elu for Q,K; col segment of N=3072), grid 1536.
// EPI=1: plain store (ctx GEMM, Bt per-batch: Bt + batch*1M), grid 512.
template <int EPI>
__global__ __launch_bounds__(512, 2) void k_gemm8(
    const u16* __restrict__ A, const u16* __restrict__ Bt,
    u16* __restrict__ o0, u16* __restrict__ o1, u16* __restrict__ o2,
    const float* __restrict__ bias0, const float* __restrict__ bias1,
    const float* __restrict__ bias2) {
  __shared__ __align__(16) char lds[131072];
  const int tid = threadIdx.x;
  const int w = tid >> 6, l = tid & 63;
  const int wm = w >> 2, wn = w & 3;

  // L2-locality remap: virt = chunked-XCD id; order (g, bx, by-group-of-4).
  const int bid = (int)blockIdx.x;
  int bx, by;
  if (EPI == 0) {  // 1536 blocks
    const int virt = (bid & 7) * 192 + (bid >> 3);
    const int g = virt / 512;        // Q/K/V segment group
    const int r = virt - g * 512;    // 0..511
    bx = r >> 2;                     // 0..127
    by = g * 4 + (r & 3);            // 0..11
  } else {         // 512 blocks
    const int virt = (bid & 7) * 64 + (bid >> 3);
    bx = virt >> 2;                  // 0..127
    by = virt & 3;                   // 0..3
  }
  const long row0 = (long)bx * 256;
  const long col0 = (long)by * 256;
  const u16* Bt2 = Bt + (EPI == 1 ? ((size_t)(row0 >> 12) << 20) : (size_t)0);

  // --- staging source pointers (per thread); source pre-swizzled (st_16x32).
  const int rS = (tid >> 2) & 127;
  const int koff = ((tid & 3) * 16) ^ ((tid & 32) ? 32 : 0);  // bytes
  const u16* srcA =
      A + (row0 + (rS & 63) + ((rS >> 6) << 7)) * 1024 + (koff >> 1);
  const u16* srcB =
      Bt2 + (col0 + (rS & 31) + ((rS >> 5) << 6)) * 1024 + (koff >> 1);

#define STAGE_A(buf, mh, t)                                              \
  do {                                                                   \
    const u16* s_ = srcA + (mh)*65536 + (size_t)(t)*64;                  \
    char* d_ = lds + (buf)*65536 + (mh)*16384 + w * 1024;                \
    gload16(s_, d_);                                                     \
    gload16(s_ + 32, d_ + 8192);                                         \
  } while (0)
#define STAGE_B(buf, bh, t)                                              \
  do {                                                                   \
    const u16* s_ = srcB + (bh)*32768 + (size_t)(t)*64;                  \
    char* d_ = lds + (buf)*65536 + 32768 + (bh)*16384 + w * 1024;        \
    gload16(s_, d_);                                                     \
    gload16(s_ + 32, d_ + 8192);                                         \
  } while (0)

  // --- LDS read addressing (swizzled): row r -> byte r*64 + (kbyte^((r&8)?32:0))
  const int rkoff = ((l >> 4) * 16) ^ ((l & 8) ? 32 : 0);
  const int aro = wm * 4096 + (l & 15) * 64 + rkoff;
  const int bro = wn * 2048 + (l & 15) * 64 + rkoff;

  bf16x8 a[4][2], b0r[2][2], b1r[2][2];
  f32x4 acc[8][4];
#pragma unroll
  for (int i = 0; i < 8; ++i)
#pragma unroll
    for (int j = 0; j < 4; ++j) acc[i][j] = (f32x4){0.f, 0.f, 0.f, 0.f};

#define LDA_(buf, mh)                                                    \
  do {                                                                   \
    const char* p_ = lds + (buf)*65536 + (mh)*16384 + aro;               \
    _Pragma("unroll") for (int mf = 0; mf < 4; ++mf)                     \
        _Pragma("unroll") for (int kh = 0; kh < 2; ++kh) a[mf][kh] =     \
        *(const bf16x8*)(p_ + mf * 1024 + kh * 8192);                    \
  } while (0)
#define LDB_(buf, nh, breg)                                              \
  do {                                                                   \
    const char* p_ = lds + (buf)*65536 + 32768 + (nh)*16384 + bro;       \
    _Pragma("unroll") for (int nf = 0; nf < 2; ++nf)                     \
        _Pragma("unroll") for (int kh = 0; kh < 2; ++kh) breg[nf][kh] =  \
        *(const bf16x8*)(p_ + nf * 1024 + kh * 8192);                    \
  } while (0)
#define MFMA_Q(mh, nh, breg)                                             \
  do {                                                                   \
    SCHEDBAR;                                                            \
    __builtin_amdgcn_s_setprio(1);                                       \
    _Pragma("unroll") for (int mf = 0; mf < 4; ++mf)                     \
        _Pragma("unroll") for (int nf = 0; nf < 2; ++nf)                 \
            _Pragma("unroll") for (int kh = 0; kh < 2; ++kh)             \
                acc[(mh)*4 + mf][(nh)*2 + nf] =                          \
        __builtin_amdgcn_mfma_f32_16x16x32_bf16(                         \
            a[mf][kh], breg[nf][kh], acc[(mh)*4 + mf][(nh)*2 + nf], 0,   \
            0, 0);                                                       \
    __builtin_amdgcn_s_setprio(0);                                       \
  } while (0)

  // Prologue: tile0 all 4 halves, tile1 first 3 halves; wait tile0; barrier.
  STAGE_A(0, 0, 0); STAGE_B(0, 0, 0); STAGE_A(0, 1, 0); STAGE_B(0, 1, 0);
  STAGE_A(1, 0, 1); STAGE_B(1, 0, 1); STAGE_A(1, 1, 1);
  asm volatile("s_waitcnt vmcnt(6)" ::: "memory");
  BAR;

#pragma unroll 2
  for (int t = 0; t < 16; ++t) {
    const int buf = t & 1;
    // ---- phase 1: Q00. reads A-h0(t), B-h0(t); stage B-h1(t+1)
    LDA_(buf, 0);
    LDB_(buf, 0, b0r);
    if (t + 1 < 16) STAGE_B(buf ^ 1, 1, t + 1);
    asm volatile("s_waitcnt lgkmcnt(8)" ::: "memory");
    BAR;
    WAITLGKM0;
    MFMA_Q(0, 0, b0r);
    BAR;
    // ---- phase 2: Q01. reads B-h1(t); stage A-h0(t+2)
    LDB_(buf, 1, b1r);
    if (t + 2 < 16) STAGE_A(buf, 0, t + 2);
    BAR;
    WAITLGKM0;
    MFMA_Q(0, 1, b1r);
    BAR;
    // ---- phase 3: Q10. reads A-h1(t); stage B-h0(t+2)
    LDA_(buf, 1);
    if (t + 2 < 16) STAGE_B(buf, 0, t + 2);
    BAR;
    WAITLGKM0;
    MFMA_Q(1, 0, b0r);
    BAR;
    // ---- phase 4: Q11. no reads; stage A-h1(t+2); counted vmcnt
    if (t + 2 < 16) {
      STAGE_A(buf, 1, t + 2);
      asm volatile("s_waitcnt vmcnt(6)" ::: "memory");
    } else {
      asm volatile("s_waitcnt vmcnt(0)" ::: "memory");
    }
    BAR;
    MFMA_Q(1, 1, b1r);
    BAR;
  }

  // ---- Epilogue: stage C (bf16) into LDS, then coalesced dwordx4 stores.
  // LDS C layout: u16[256][256] with col-group XOR swizzle:
  //   u16 index = row*256 + (cg ^ (row&7))*16 + (col&15),  cg = col>>4.
  u16* cl = (u16*)lds;
  const int seg = (EPI == 0) ? (int)(col0 >> 10) : 0;  // 0:Q 1:K 2:V
  const float* bias =
      (EPI == 0) ? ((seg == 0) ? bias0 : (seg == 1) ? bias1 : bias2) : nullptr;
  const int clb = (EPI == 0) ? ((int)(col0 & 1023) + wn * 64 + (l & 15)) : 0;
  const int rbase = wm * 128 + ((l >> 4) << 2);
  const int cgrp0 = wn * 4;
#pragma unroll
  for (int Nf = 0; Nf < 4; ++Nf) {
    const float bv_ = (EPI == 0) ? bias[clb + Nf * 16] : 0.f;
#pragma unroll
    for (int Mf = 0; Mf < 8; ++Mf)
#pragma unroll
      for (int r = 0; r < 4; ++r) {
        const int row = rbase + Mf * 16 + r;
        float v = acc[Mf][Nf][r];
        if (EPI == 0) {
          v += bv_;
          if (seg < 2) v = v > 0.f ? v : expm1f(v);  // elu
        }
        cl[row * 256 + ((cgrp0 + Nf) ^ (row & 7)) * 16 + (l & 15)] = f2bf(v);
      }
  }
  WAITLGKM0;  // own ds_writes done
  BAR;        // all waves' C visible
  // Read back row-linear: store i covers rows w*32+i*2+{0,1}; lanes 0..31 ->
  // row r0 (512B contiguous), lanes 32..63 -> row r0+1.
  // For EPI=0 Q/K: cols (l&31)*8..+7 lie in head (l&31)>>3; the 8 lanes
  // {l^1,l^2,l^4} cover that head's 64 cols of this row -> fused L2 norm.
  u16* outp = (EPI == 0) ? ((seg == 0) ? o0 : (seg == 1) ? o1 : o2) : o0;
  const int colseg = (EPI == 0) ? (int)(col0 & 1023) : (int)col0;
  const int cg = (l & 31) >> 1;           // 32B col-group
  const int lo = (l & 1) << 4;            // byte within group
#pragma unroll
  for (int i = 0; i < 16; ++i) {
    const int row = w * 32 + i * 2 + (l >> 5);
    u16x8 val = *(const u16x8*)((const char*)cl + row * 512 +
                                ((cg ^ (row & 7)) << 5) + lo);
    if (EPI == 0 && seg < 2) {
      float f[8], ss = 0.f;
#pragma unroll
      for (int j = 0; j < 8; ++j) { f[j] = bf2f(val[j]); ss += f[j] * f[j]; }
      ss += __shfl_xor(ss, 1);
      ss += __shfl_xor(ss, 2);
      ss += __shfl_xor(ss, 4);
      const float rn = rsqrtf(ss);
#pragma unroll
      for (int j = 0; j < 8; ++j) val[j] = f2bf(f[j] * rn);
    }
    *(u16x8*)(outp + (size_t)(row0 + row) * 1024 + colseg + (l & 31) * 8) = val;
  }
#undef STAGE_A
#undef STAGE_B
#undef LDA_
#undef LDB_
#undef MFMA_Q
}

// ---------------------------------------------------------------------------
// kv partials: kvp[sc][b][h][d][e] = sum over s-chunk of kn[s,d]*v[s,e]
// (kn is pre-normalized by the QKV epilogue)
__global__ __launch_bounds__(256) void k_kv(const u16* __restrict__ kn,
                                            const u16* __restrict__ vv,
                                            float* __restrict__ kvp) {
  __shared__ float kns[64][68];  // +4 pad: conflict-free staging & reads
  __shared__ float vs[64][68];
  const int tid = threadIdx.x;
  const int bid = blockIdx.x;  // sc + 4*(h + 16*b)
  const int sc = bid & 3, h = (bid >> 2) & 15, b = bid >> 6;
  const int d = tid >> 2, eg = tid & 3;
  float acc[16] = {};
  const long tbase = (long)b * 4096 + sc * 1024;
  for (int st = 0; st < 1024; st += 64) {
    const long t = tbase + st + (tid >> 2);
    const int q = tid & 3;
    const u16* ep = kn + (size_t)t * 1024 + h * 64 + q * 16;
    const u16* vp = vv + (size_t)t * 1024 + h * 64 + q * 16;
    u16x8 e0 = *(const u16x8*)ep, e1 = *(const u16x8*)(ep + 8);
    u16x8 v0 = *(const u16x8*)vp, v1 = *(const u16x8*)(vp + 8);
    __syncthreads();  // previous tile fully consumed
#pragma unroll
    for (int j = 0; j < 8; ++j) {
      kns[tid >> 2][q * 16 + j] = bf2f(e0[j]);
      kns[tid >> 2][q * 16 + 8 + j] = bf2f(e1[j]);
      vs[tid >> 2][q * 16 + j] = bf2f(v0[j]);
      vs[tid >> 2][q * 16 + 8 + j] = bf2f(v1[j]);
    }
    __syncthreads();
    for (int s = 0; s < 64; ++s) {
      const float knv = kns[s][d];
      const f32x4* vr = (const f32x4*)&vs[s][eg * 16];
      f32x4 q0 = vr[0], q1 = vr[1], q2 = vr[2], q3 = vr[3];
#pragma unroll
      for (int j = 0; j < 4; ++j) {
        acc[j] += knv * q0[j];
        acc[4 + j] += knv * q1[j];
        acc[8 + j] += knv * q2[j];
        acc[12 + j] += knv * q3[j];
      }
    }
  }
  float* op = kvp + (((size_t)(sc * 8 + b) * 16 + h) * 64 + d) * 64 + eg * 16;
#pragma unroll
  for (int c = 0; c < 4; ++c) {
    f32x4 o = {acc[c * 4], acc[c * 4 + 1], acc[c * 4 + 2], acc[c * 4 + 3]};
    *(f32x4*)(op + c * 4) = o;
  }
}

// ---------------------------------------------------------------------------
// M2t[b][n][h*64+d] = (1/8) * sum_e kv[b,h][d][e] * Wd[h*64+e][n]   (bf16)
__global__ __launch_bounds__(256) void k_m2(const float* __restrict__ kvp,
                                            const float* __restrict__ Wd,
                                            u16* __restrict__ M2t) {
  const int tid = threadIdx.x;
  const int nb = blockIdx.x, h = blockIdx.y, b = blockIdx.z;
  const int d = tid >> 2, eg = tid & 3;
  const size_t kbase = (((size_t)(b * 16 + h)) * 64 + d) * 64 + eg * 16;
  float kvr[16];
#pragma unroll
  for (int c = 0; c < 4; ++c) {
    f32x4 s = *(const f32x4*)(kvp + kbase + c * 4);
#pragma unroll
    for (int sc = 1; sc < 4; ++sc)
      s += *(const f32x4*)(kvp + (size_t)sc * 524288 + kbase + c * 4);
#pragma unroll
    for (int j = 0; j < 4; ++j) kvr[c * 4 + j] = s[j];
  }
  const float* wcol = Wd + ((size_t)h * 64 + eg * 16) * 1024;
  for (int n = nb * 256; n < nb * 256 + 256; ++n) {
    float p = 0.f;
#pragma unroll
    for (int i = 0; i < 16; ++i) p += kvr[i] * wcol[(size_t)i * 1024 + n];
    p += __shfl_xor(p, 1);
    p += __shfl_xor(p, 2);
    if (eg == 0)
      M2t[((size_t)b * 1024 + n) * 1024 + h * 64 + d] = f2bf(p * 0.125f);
  }
}

// ---------------------------------------------------------------------------
// LayerNorm(hid + bd + xb) * gamma + beta  -> fp32 out  (residual from bf16 Xb)
__global__ __launch_bounds__(256) void k_ln(const u16* __restrict__ hid,
                                            const u16* __restrict__ xb,
                                            const float* __restrict__ bd,
                                            const float* __restrict__ g,
                                            const float* __restrict__ be,
                                            float* __restrict__ out) {
  const int tid = threadIdx.x, w = tid >> 6, l = tid & 63;
  const size_t base = (size_t)blockIdx.x * 1024 + tid * 4;
  u16x4 h4 = *(const u16x4*)(hid + base);
  u16x4 x4 = *(const u16x4*)(xb + base);
  f32x4 bd4 = *(const f32x4*)(bd + tid * 4);
  float v[4];
#pragma unroll
  for (int j = 0; j < 4; ++j) v[j] = bf2f(h4[j]) + bf2f(x4[j]) + bd4[j];
  float s = v[0] + v[1] + v[2] + v[3];
  float ss = v[0] * v[0] + v[1] * v[1] + v[2] * v[2] + v[3] * v[3];
#pragma unroll
  for (int o = 32; o > 0; o >>= 1) {
    s += __shfl_xor(s, o);
    ss += __shfl_xor(ss, o);
  }
  __shared__ float red[8];
  if (l == 0) { red[w] = s; red[w + 4] = ss; }
  __syncthreads();
  s = red[0] + red[1] + red[2] + red[3];
  ss = red[4] + red[5] + red[6] + red[7];
  const float mu = s * (1.0f / 1024.0f);
  const float var = ss * (1.0f / 1024.0f) - mu * mu;
  const float rstd = rsqrtf(var + 1e-12f);
  f32x4 g4 = *(const f32x4*)(g + tid * 4);
  f32x4 b4 = *(const f32x4*)(be + tid * 4);
  f32x4 o;
#pragma unroll
  for (int j = 0; j < 4; ++j) o[j] = (v[j] - mu) * rstd * g4[j] + b4[j];
  *(f32x4*)(out + base) = o;
}

// ---------------------------------------------------------------------------
extern "C" void kernel_launch(void* const* d_in, const int* in_sizes, int n_in,
                              void* d_out, int out_size, void* d_ws,
                              size_t ws_size, hipStream_t stream) {
  const float* X = (const float*)d_in[0];
  const float* Wq = (const float*)d_in[1];
  const float* bq = (const float*)d_in[2];
  const float* Wk = (const float*)d_in[3];
  const float* bk = (const float*)d_in[4];
  const float* Wv = (const float*)d_in[5];
  const float* bv = (const float*)d_in[6];
  const float* Wd = (const float*)d_in[7];
  const float* bd = (const float*)d_in[8];
  const float* gamma = (const float*)d_in[9];
  const float* beta = (const float*)d_in[10];
  float* out = (float*)d_out;

  char* ws = (char*)d_ws;
  u16* Xb = (u16*)(ws);                       // 64 MiB
  u16* Wt = (u16*)(ws + 67108864);            // 6 MiB  [3072][1024] bf16
  u16* eq = (u16*)(ws + 73400320);            // 64 MiB (qn, normalized in epi)
  u16* ek = (u16*)(ws + 140509184);           // 64 MiB (kn; reused as hid)
  u16* vb = (u16*)(ws + 207618048);           // 64 MiB
  float* kvp = (float*)(ws + 276824064);      // 8 MiB (4 partials)
  u16* M2t = (u16*)(ws + 285212672);          // 16 MiB  [8][1024][1024] bf16
  // total ws use: 301,989,888 bytes

  k_cvt_x<<<16384, 256, 0, stream>>>(X, Xb);
  k_wt<<<dim3(4, 128, 3), 256, 0, stream>>>(Wq, Wk, Wv, Wt);
  k_gemm8<0><<<1536, 512, 0, stream>>>(Xb, Wt, eq, ek, vb, bq, bk, bv);
  k_kv<<<512, 256, 0, stream>>>(ek, vb, kvp);
  k_m2<<<dim3(4, 16, 8), 256, 0, stream>>>(kvp, Wd, M2t);
  k_gemm8<1><<<512, 512, 0, stream>>>(eq, M2t, ek, nullptr, nullptr, nullptr,
                                      nullptr, nullptr);
  k_ln<<<32768, 256, 0, stream>>>(ek, Xb, bd, gamma, beta, out);
}